// Round 10
// baseline (430.185 us; speedup 1.0000x reference)
//
#include <hip/hip_runtime.h>
#include <hip/hip_bf16.h>

// EdgeConv B=8,C=64,N=4096,OUT=64,K=20.
// h[b,o,n,k] = z[b,n,o] - y[b,idx_k,o];  out = leakyrelu((z - min/max_k y)*inv + bias)
#define NN 4096
#define KK 20
#define LL 12        // per-thread sorted list of GROUP keys (group = 4 consecutive m)
#define KP 196       // keysL row pitch in dwords (192 keys + 4 pad)
#define EXTRG 24     // groups merged out before rescore (exact: bearing groups are top-<=20)
#define NF 24        // fp64-rescored finalists

typedef short bf16x8 __attribute__((ext_vector_type(8)));
typedef float f32x4  __attribute__((ext_vector_type(4)));

__device__ __forceinline__ unsigned umax_(unsigned a, unsigned b){ return a > b ? a : b; }
__device__ __forceinline__ unsigned umin_(unsigned a, unsigned b){ return a < b ? a : b; }

__device__ __forceinline__ unsigned bfbits(float f) {   // fp32 -> bf16 bits, RNE
    unsigned u = __float_as_uint(f);
    return (u + 0x7FFFu + ((u >> 16) & 1u)) >> 16;
}
__device__ __forceinline__ float bflo(unsigned u){ return __builtin_bit_cast(float, u << 16); }
__device__ __forceinline__ float bfhi(unsigned u){ return __builtin_bit_cast(float, u & 0xFFFF0000u); }

__device__ __forceinline__ uint4 packfrag_u(float4 lo, float4 hi) {
    return make_uint4(bfbits(lo.x) | (bfbits(lo.y) << 16),
                      bfbits(lo.z) | (bfbits(lo.w) << 16),
                      bfbits(hi.x) | (bfbits(hi.y) << 16),
                      bfbits(hi.z) | (bfbits(hi.w) << 16));
}

// ---- DPP cross-lane (row = 16 lanes; row_ror:n = 0x120+n) -------------------
template<int CTRL>
__device__ __forceinline__ int dpp_mov(int v) {
    return __builtin_amdgcn_update_dpp(0, v, CTRL, 0xF, 0xF, true);
}
template<int CTRL>
__device__ __forceinline__ float dpp_addf(float v) {
    return v + __builtin_bit_cast(float, dpp_mov<CTRL>(__builtin_bit_cast(int, v)));
}
template<int CTRL>
__device__ __forceinline__ unsigned dpp_maxu(unsigned v) {
    return umax_(v, (unsigned)dpp_mov<CTRL>((int)v));
}
__device__ __forceinline__ float rowsum16(float v) {
    v = dpp_addf<0x128>(v); v = dpp_addf<0x124>(v);
    v = dpp_addf<0x122>(v); v = dpp_addf<0x121>(v);
    return v;
}
__device__ __forceinline__ unsigned rowmax16(unsigned v) {
    v = dpp_maxu<0x128>(v); v = dpp_maxu<0x124>(v);
    v = dpp_maxu<0x122>(v); v = dpp_maxu<0x121>(v);
    return v;
}

// ---------------- Kernel 0: pre-pack W bf16 MFMA fragments (runs once, tiny) ----------
// Wf[(o)*16 + sel*4 + quad], sel in {w1a,w1b,w2a,w2b} <-> W4 col offset sel*8.
__global__ __launch_bounds__(256) void k_prepW(
    const float* __restrict__ W, uint4* __restrict__ Wf)
{
    const float4* W4 = (const float4*)W;       // W row = 32 float4
    int t = threadIdx.x;
    #pragma unroll
    for (int it = 0; it < 4; ++it) {
        int idx = it*256 + t;                  // 0..1023
        int o = idx >> 4, sel = (idx >> 2) & 3, quad = idx & 3;
        float4 lo = W4[(size_t)o*32 + sel*8 + quad*2];
        float4 hi = W4[(size_t)o*32 + sel*8 + quad*2 + 1];
        Wf[idx] = packfrag_u(lo, hi);
    }
}

// ---------------- Kernel 1a: transpose + xx + bf16, line-coalesced stores ----------------
__global__ __launch_bounds__(128) void k_prep1(
    const float* __restrict__ x,
    float* __restrict__ xt, unsigned short* __restrict__ xbf,
    double* __restrict__ xxd, float* __restrict__ xxc)
{
    __shared__ __align__(16) float tS[128 * 33];
    int tid = threadIdx.x;
    int b   = blockIdx.x >> 5;
    int nb0 = (blockIdx.x & 31) << 7;
    int n   = nb0 + tid;
    size_t brow = (size_t)b * NN;

    float xv[64];
    double xx = 0.0;
    #pragma unroll
    for (int cc = 0; cc < 64; ++cc) {
        float v = x[((size_t)(b*64 + cc) << 12) + n];
        xv[cc] = v;
        xx += (double)v * (double)v;
    }
    xxd[brow + n] = xx;
    xxc[brow + n] = 1024.f - (float)xx;     // biased so scores are always > 0

    // fp32 xt: two 32-channel halves through LDS
    #pragma unroll 1
    for (int h = 0; h < 2; ++h) {
        #pragma unroll
        for (int cc = 0; cc < 32; ++cc) tS[tid*33 + cc] = xv[h*32 + cc];
        __syncthreads();
        #pragma unroll
        for (int i = 0; i < 8; ++i) {
            int idx = i*128 + tid;              // 0..1023 float4s
            int r = idx >> 3, c4 = idx & 7;
            float4 v = make_float4(tS[r*33 + 4*c4],     tS[r*33 + 4*c4 + 1],
                                   tS[r*33 + 4*c4 + 2], tS[r*33 + 4*c4 + 3]);
            *(float4*)(xt + (brow + nb0 + r)*64 + h*32 + 4*c4) = v;
        }
        __syncthreads();
    }
    // bf16 xbf through LDS
    {
        unsigned pk[32];
        #pragma unroll
        for (int i = 0; i < 32; ++i)
            pk[i] = bfbits(xv[2*i]) | (bfbits(xv[2*i+1]) << 16);
        unsigned* tU = (unsigned*)tS;
        #pragma unroll
        for (int i = 0; i < 32; ++i) tU[tid*33 + i] = pk[i];
        __syncthreads();
        uint4* xb4 = (uint4*)xbf;
        #pragma unroll
        for (int i = 0; i < 8; ++i) {
            int idx = i*128 + tid;
            int r = idx >> 3, u4 = idx & 7;
            uint4 v = make_uint4(tU[r*33 + 4*u4],     tU[r*33 + 4*u4 + 1],
                                 tU[r*33 + 4*u4 + 2], tU[r*33 + 4*u4 + 3]);
            xb4[(brow + nb0 + r)*8 + u4] = v;
        }
    }
}

// ---------------- Kernel 1b: y/z via MFMA from xbf + prepacked W fragments ----------------
__global__ __launch_bounds__(256) void k_prep2(
    const uint4* __restrict__ Wf, const unsigned short* __restrict__ xbf,
    unsigned short* __restrict__ ybf, unsigned short* __restrict__ zbf)
{
    int tid = threadIdx.x;
    int wv = blockIdx.x * 4 + (tid >> 6);      // 0..2047
    int lane = tid & 63, quad = lane >> 4, c = lane & 15;
    int b = wv >> 8, n0 = (wv & 255) << 4;
    size_t brow = (size_t)b * NN;

    const uint4* xb = (const uint4*)xbf;
    size_t nrow = (brow + n0 + c) * 8 + quad;
    bf16x8 bb0 = __builtin_bit_cast(bf16x8, xb[nrow]);
    bf16x8 bb1 = __builtin_bit_cast(bf16x8, xb[nrow + 4]);

    #pragma unroll 1
    for (int ot = 0; ot < 4; ++ot) {
        const uint4* wf = Wf + (size_t)(ot*16 + c)*16 + quad;
        bf16x8 w1a = __builtin_bit_cast(bf16x8, wf[0]);
        bf16x8 w1b = __builtin_bit_cast(bf16x8, wf[4]);
        bf16x8 w2a = __builtin_bit_cast(bf16x8, wf[8]);
        bf16x8 w2b = __builtin_bit_cast(bf16x8, wf[12]);
        f32x4 acc1 = __builtin_amdgcn_mfma_f32_16x16x32_bf16(
            w1a, bb0, (f32x4){0.f,0.f,0.f,0.f}, 0, 0, 0);
        acc1 = __builtin_amdgcn_mfma_f32_16x16x32_bf16(w1b, bb1, acc1, 0, 0, 0);
        f32x4 acc2 = __builtin_amdgcn_mfma_f32_16x16x32_bf16(
            w2a, bb0, (f32x4){0.f,0.f,0.f,0.f}, 0, 0, 0);
        acc2 = __builtin_amdgcn_mfma_f32_16x16x32_bf16(w2b, bb1, acc2, 0, 0, 0);
        float z0 = acc1[0]+acc2[0], z1 = acc1[1]+acc2[1],
              z2 = acc1[2]+acc2[2], z3 = acc1[3]+acc2[3];
        size_t obase = (brow + n0 + c) * 64 + (ot*16 + quad*4);
        *(uint2*)(ybf + obase) = make_uint2(
            bfbits(acc1[0]) | (bfbits(acc1[1]) << 16),
            bfbits(acc1[2]) | (bfbits(acc1[3]) << 16));
        *(uint2*)(zbf + obase) = make_uint2(
            bfbits(z0) | (bfbits(z1) << 16),
            bfbits(z2) | (bfbits(z3) << 16));
    }
}

// ---------------- Kernel 2 (fused): 32-n tile Gram + top-12 keys + refine ----------------
// 1024 blocks x 256. LDS = 24.0 KB -> 6 blocks/CU (R9's 39.9 KB capped at 4; VALUBusy
// 49% showed waves starved). Two 16-row key batches share one keysL buffer.
__global__ __launch_bounds__(256, 6) void k_main(
    const unsigned short* __restrict__ xbf, const float* __restrict__ xt,
    const double* __restrict__ xxd, const float* __restrict__ xxc,
    const unsigned short* __restrict__ ybf, const unsigned short* __restrict__ zbf,
    const float* __restrict__ gamma, const float* __restrict__ beta,
    const float* __restrict__ rmean, const float* __restrict__ rvar,
    float* __restrict__ out)
{
    __shared__ __align__(16) unsigned keysL[16 * KP];     // 12544 B (outS aliases this)
    __shared__ __align__(16) unsigned gselS[32 * EXTRG];  // 3072 B
    __shared__ unsigned short m26S[32 * NF];              // 1536 B
    __shared__ double   d26S[32 * NF];                    // 6144 B
    __shared__ unsigned short selS[32 * KK];              // 1280 B
    float* outS = (float*)keysL;                          // 64 o x pitch 33 = 8448 B

    int tid  = threadIdx.x;
    int w    = tid >> 6, lane = tid & 63;
    int quad = lane >> 4, c = lane & 15;
    int b  = blockIdx.x & 7;                 // batch <-> XCD affinity
    int n0 = (blockIdx.x >> 3) << 5;         // 32-n tile
    size_t brow = (size_t)b * NN;

    const uint4* xb = (const uint4*)xbf;     // one row = 8 uint4

    // B fragments for the two fixed n-tiles
    size_t nr0 = (brow + n0 + c) * 8 + quad;
    size_t nr1 = (brow + n0 + 16 + c) * 8 + quad;
    bf16x8 b00 = __builtin_bit_cast(bf16x8, xb[nr0]);
    bf16x8 b01 = __builtin_bit_cast(bf16x8, xb[nr0 + 4]);
    bf16x8 b10 = __builtin_bit_cast(bf16x8, xb[nr1]);
    bf16x8 b11 = __builtin_bit_cast(bf16x8, xb[nr1 + 4]);

    unsigned kA[LL], kB[LL];
    #pragma unroll
    for (int i = 0; i < LL; ++i) { kA[i] = 0u; kB[i] = 0u; }

    // A stream, prefetch depth 2
    size_t abase = (brow + 16*w + c) * 8 + quad;
    size_t xxb   = brow + 16*w + quad*4;
    uint4  a0p[2], a1p[2];
    float4 xxp[2];
    a0p[0] = xb[abase];       a1p[0] = xb[abase + 4];
    a0p[1] = xb[abase + 512]; a1p[1] = xb[abase + 516];
    xxp[0] = *(const float4*)(xxc + xxb);
    xxp[1] = *(const float4*)(xxc + xxb + 64);

    #pragma unroll 2
    for (int chunk = 0; chunk < 64; ++chunk) {
        int s = chunk & 1;                   // constant after unroll-2
        uint4 ca0 = a0p[s], ca1 = a1p[s];
        float4 x4 = xxp[s];
        if (chunk < 62) {
            size_t nb = abase + (size_t)(chunk + 2) * 512;
            a0p[s] = xb[nb]; a1p[s] = xb[nb + 4];
            xxp[s] = *(const float4*)(xxc + xxb + (chunk + 2)*64);
        }
        f32x4 accA = __builtin_amdgcn_mfma_f32_16x16x32_bf16(
            __builtin_bit_cast(bf16x8, ca0), b00, (f32x4){0.f,0.f,0.f,0.f}, 0, 0, 0);
        accA = __builtin_amdgcn_mfma_f32_16x16x32_bf16(
            __builtin_bit_cast(bf16x8, ca1), b01, accA, 0, 0, 0);
        f32x4 accB = __builtin_amdgcn_mfma_f32_16x16x32_bf16(
            __builtin_bit_cast(bf16x8, ca0), b10, (f32x4){0.f,0.f,0.f,0.f}, 0, 0, 0);
        accB = __builtin_amdgcn_mfma_f32_16x16x32_bf16(
            __builtin_bit_cast(bf16x8, ca1), b11, accB, 0, 0, 0);

        unsigned gid = (unsigned)((chunk << 4) | (w << 2) | quad);
        {   // tile 0: n = n0+c
            float s0 = fmaf(2.f, accA[0], x4.x), s1 = fmaf(2.f, accA[1], x4.y);
            float s2 = fmaf(2.f, accA[2], x4.z), s3 = fmaf(2.f, accA[3], x4.w);
            float gm = fmaxf(fmaxf(s0, s1), fmaxf(s2, s3));
            unsigned key = (__float_as_uint(gm) & 0xFFFFFC00u) | gid;
            #pragma unroll
            for (int t = 0; t < LL; ++t) {
                unsigned mx = umax_(kA[t], key);
                key = umin_(kA[t], key);
                kA[t] = mx;
            }
        }
        {   // tile 1: n = n0+16+c (independent chain, interleaves)
            float s0 = fmaf(2.f, accB[0], x4.x), s1 = fmaf(2.f, accB[1], x4.y);
            float s2 = fmaf(2.f, accB[2], x4.z), s3 = fmaf(2.f, accB[3], x4.w);
            float gm = fmaxf(fmaxf(s0, s1), fmaxf(s2, s3));
            unsigned key = (__float_as_uint(gm) & 0xFFFFFC00u) | gid;
            #pragma unroll
            for (int t = 0; t < LL; ++t) {
                unsigned mx = umax_(kB[t], key);
                key = umin_(kB[t], key);
                kB[t] = mx;
            }
        }
    }

    int r = tid >> 4, g = tid & 15;

    // ---- two-phase park + merge through a single 16-row keysL ----
    #pragma unroll 1
    for (int phase = 0; phase < 2; ++phase) {
        uint4* kd = (uint4*)(keysL + c*KP + (w*4 + quad)*LL);
        if (phase == 0) {
            kd[0] = make_uint4(kA[0], kA[1], kA[2],  kA[3]);
            kd[1] = make_uint4(kA[4], kA[5], kA[6],  kA[7]);
            kd[2] = make_uint4(kA[8], kA[9], kA[10], kA[11]);
        } else {
            kd[0] = make_uint4(kB[0], kB[1], kB[2],  kB[3]);
            kd[1] = make_uint4(kB[4], kB[5], kB[6],  kB[7]);
            kd[2] = make_uint4(kB[8], kB[9], kB[10], kB[11]);
        }
        __syncthreads();
        // merge: quarter-wave r handles row r of this phase
        unsigned mk[LL];
        {
            const uint4* ks = (const uint4*)(keysL + r*KP + g*LL);
            uint4 k0 = ks[0], k1 = ks[1], k2 = ks[2];
            mk[0]=k0.x; mk[1]=k0.y; mk[2]=k0.z;  mk[3]=k0.w;
            mk[4]=k1.x; mk[5]=k1.y; mk[6]=k1.z;  mk[7]=k1.w;
            mk[8]=k2.x; mk[9]=k2.y; mk[10]=k2.z; mk[11]=k2.w;
        }
        int grow = phase*16 + r;
        #pragma unroll 1
        for (int it = 0; it < EXTRG; ++it) {
            unsigned vm = rowmax16(mk[0]);
            bool win = (mk[0] == vm);
            #pragma unroll
            for (int q = 0; q < LL-1; ++q) mk[q] = win ? mk[q+1] : mk[q];
            mk[LL-1] = win ? 0u : mk[LL-1];
            if (g == (it & 15)) gselS[grow*EXTRG + it] = vm;
        }
        __syncthreads();
    }

    // ================= refine pass 2 (stages 3..6 per row) =================
    #pragma unroll 1
    for (int rr = 0; rr < 2; ++rr) {
        int row = rr*16 + r;
        int n = n0 + row;
        uint2 anb = *(const uint2*)(xbf + (brow + n) * 64 + 4*g);
        float an0 = bflo(anb.x), an1 = bfhi(anb.x),
              an2 = bflo(anb.y), an3 = bfhi(anb.y);

        // stage 3: bf16 cooperative rescore of 96 candidates
        unsigned myk[6];
        #pragma unroll
        for (int j = 0; j < 6; ++j) {
            uint4 Gj = *(const uint4*)(gselS + row*EXTRG + 4*j);
            unsigned gk4[4] = {Gj.x, Gj.y, Gj.z, Gj.w};
            #pragma unroll
            for (int h = 0; h < 2; ++h) {
                uint2 vbs[8]; float xxm[8];
                #pragma unroll
                for (int u = 0; u < 8; ++u) {
                    int t = h*8 + u;
                    int m = (int)((gk4[t >> 2] & 1023u) << 2) | (t & 3);
                    vbs[u] = *(const uint2*)(xbf + (brow + m) * 64 + 4*g);
                    xxm[u] = xxc[brow + m];
                }
                #pragma unroll
                for (int u = 0; u < 8; ++u) {
                    int t = h*8 + u;
                    float p = an0 * bflo(vbs[u].x);
                    p = fmaf(an1, bfhi(vbs[u].x), p);
                    p = fmaf(an2, bflo(vbs[u].y), p);
                    p = fmaf(an3, bfhi(vbs[u].y), p);
                    p = rowsum16(p);
                    float sc = fmaf(2.f, p, xxm[u]);
                    unsigned key = (__float_as_uint(sc) & 0xFFFFFF80u) | (unsigned)(j*16 + t);
                    if (t == g) myk[j] = key;
                }
            }
        }
        #pragma unroll
        for (int a = 1; a < 6; ++a)
            #pragma unroll
            for (int q = a; q > 0; --q) {
                unsigned lo = umin_(myk[q-1], myk[q]);
                myk[q-1] = umax_(myk[q-1], myk[q]);
                myk[q] = lo;
            }

        // stage 3.5: pop-shift merge -> exact top-NF of the 96 fp32 keys
        #pragma unroll 1
        for (int it = 0; it < NF; ++it) {
            unsigned vm = rowmax16(myk[0]);
            bool win = (myk[0] == vm);
            #pragma unroll
            for (int q = 0; q < 5; ++q) myk[q] = win ? myk[q+1] : myk[q];
            myk[5] = win ? 0u : myk[5];
            if (g == (it & 15)) {
                int i = (int)(vm & 127u);
                unsigned gk = gselS[row*EXTRG + (i >> 2)];
                m26S[row*NF + it] = (unsigned short)(((gk & 1023u) << 2) | (i & 3));
            }
        }

        // stage 4: fp64 per-lane full dots, dual accumulators (halved dep chain)
        #pragma unroll
        for (int round = 0; round < 2; ++round) {
            int t = round*16 + g;
            if (t < NF) {
                int m = (int)m26S[row*NF + t];
                const float4* xm = (const float4*)(xt + (brow + m) * 64);
                const float4* xn = (const float4*)(xt + (brow + n) * 64);
                double acc0 = 0.0, acc1 = 0.0;
                #pragma unroll
                for (int i = 0; i < 8; ++i) {
                    float4 v0 = xm[2*i], a0 = xn[2*i];
                    float4 v1 = xm[2*i+1], a1 = xn[2*i+1];
                    acc0 += (double)a0.x*(double)v0.x + (double)a0.y*(double)v0.y
                          + (double)a0.z*(double)v0.z + (double)a0.w*(double)v0.w;
                    acc1 += (double)a1.x*(double)v1.x + (double)a1.y*(double)v1.y
                          + (double)a1.z*(double)v1.z + (double)a1.w*(double)v1.w;
                }
                d26S[row*NF + t] = 2.0*(acc0 + acc1) - xxd[brow + m];
            }
        }

        // stage 5: exact top-20 set by rank counting
        #pragma unroll
        for (int round = 0; round < 2; ++round) {
            int t = round*16 + g;
            if (t < NF) {
                double st = d26S[row*NF + t];
                int cnt = 0;
                #pragma unroll
                for (int p = 0; p < NF; ++p) cnt += (d26S[row*NF + p] > st) ? 1 : 0;
                if (cnt < KK) selS[row*KK + cnt] = m26S[row*NF + t];
            }
        }

        // stage 6: gather y (bf16), min/max per o, epilogue -> outS (aliased)
        float mn[4] = { __builtin_inff(), __builtin_inff(), __builtin_inff(), __builtin_inff() };
        float mx[4] = { -__builtin_inff(), -__builtin_inff(), -__builtin_inff(), -__builtin_inff() };
        #pragma unroll
        for (int hb = 0; hb < 2; ++hb) {
            uint2 yb[10];
            #pragma unroll
            for (int k = 0; k < 10; ++k)
                yb[k] = *(const uint2*)(ybf + (brow + (int)selS[row*KK + hb*10 + k]) * 64 + 4*g);
            #pragma unroll
            for (int k = 0; k < 10; ++k) {
                float y0 = bflo(yb[k].x), y1 = bfhi(yb[k].x),
                      y2 = bflo(yb[k].y), y3 = bfhi(yb[k].y);
                mn[0] = fminf(mn[0], y0); mx[0] = fmaxf(mx[0], y0);
                mn[1] = fminf(mn[1], y1); mx[1] = fmaxf(mx[1], y1);
                mn[2] = fminf(mn[2], y2); mx[2] = fmaxf(mx[2], y2);
                mn[3] = fminf(mn[3], y3); mx[3] = fmaxf(mx[3], y3);
            }
        }
        uint2 zb = *(const uint2*)(zbf + (brow + n) * 64 + 4*g);
        float zz[4] = {bflo(zb.x), bfhi(zb.x), bflo(zb.y), bfhi(zb.y)};
        #pragma unroll
        for (int j = 0; j < 4; ++j) {
            int o = 4*g + j;
            float inv  = gamma[o] / sqrtf(rvar[o] + 1e-5f);
            float bias = beta[o] - rmean[o] * inv;
            float ysel = (inv >= 0.f) ? mn[j] : mx[j];
            float h = (zz[j] - ysel) * inv + bias;
            outS[o*33 + row] = (h >= 0.f) ? h : 0.2f * h;
        }
    }
    __syncthreads();   // cross-wave: output transpose
    {
        int o = tid >> 2, q = tid & 3;
        float* ob = outS + o*33;
        float4 v0 = make_float4(ob[4*q],      ob[4*q + 1],  ob[4*q + 2],  ob[4*q + 3]);
        float4 v1 = make_float4(ob[16 + 4*q], ob[17 + 4*q], ob[18 + 4*q], ob[19 + 4*q]);
        float* op = out + ((size_t)(b*64 + o) << 12) + n0;
        *(float4*)(op + 4*q)      = v0;
        *(float4*)(op + 16 + 4*q) = v1;
    }
}

extern "C" void kernel_launch(void* const* d_in, const int* in_sizes, int n_in,
                              void* d_out, int out_size, void* d_ws, size_t ws_size,
                              hipStream_t stream) {
    const float* x     = (const float*)d_in[0];
    const float* W     = (const float*)d_in[1];
    const float* gamma = (const float*)d_in[2];
    const float* beta  = (const float*)d_in[3];
    const float* rmean = (const float*)d_in[4];
    const float* rvar  = (const float*)d_in[5];
    float* out = (float*)d_out;

    char* ws = (char*)d_ws;
    float*          xt  = (float*)          (ws);                          //  8 MB
    unsigned short* xbf = (unsigned short*) (ws + ((size_t) 8 << 20));     //  4 MB
    unsigned short* ybf = (unsigned short*) (ws + ((size_t)12 << 20));     //  4 MB
    unsigned short* zbf = (unsigned short*) (ws + ((size_t)16 << 20));     //  4 MB
    double*         xxd = (double*)         (ws + ((size_t)20 << 20));     // 256 KB
    float*          xxc = (float*)          (ws + ((size_t)20 << 20) + (512 << 10)); // 128 KB
    uint4*          Wf  = (uint4*)          (ws + ((size_t)21 << 20));     // 16 KB

    k_prepW<<<   1, 256, 0, stream>>>(W, Wf);
    k_prep1<<< 256, 128, 0, stream>>>(x, xt, xbf, xxd, xxc);
    k_prep2<<< 512, 256, 0, stream>>>(Wf, xbf, ybf, zbf);
    k_main <<<1024, 256, 0, stream>>>(xbf, xt, xxd, xxc, ybf, zbf,
                                      gamma, beta, rmean, rvar, out);
}

// Round 11
// 234.018 us; speedup vs baseline: 1.8383x; 1.8383x over previous
//
#include <hip/hip_runtime.h>
#include <hip/hip_bf16.h>

// EdgeConv B=8,C=64,N=4096,OUT=64,K=20.
// h[b,o,n,k] = z[b,n,o] - y[b,idx_k,o];  out = leakyrelu((z - min/max_k y)*inv + bias)
#define NN 4096
#define KK 20
#define LL 12        // per-thread sorted list of GROUP keys (group = 4 consecutive m)
#define KP 196       // keysL row pitch in dwords (192 keys + 4 pad)
#define EXTRG 24     // groups merged out before rescore (exact: bearing groups are top-<=20)
#define NF 24        // fp64-rescored finalists

typedef short bf16x8 __attribute__((ext_vector_type(8)));
typedef float f32x4  __attribute__((ext_vector_type(4)));

__device__ __forceinline__ unsigned umax_(unsigned a, unsigned b){ return a > b ? a : b; }
__device__ __forceinline__ unsigned umin_(unsigned a, unsigned b){ return a < b ? a : b; }

__device__ __forceinline__ unsigned bfbits(float f) {   // fp32 -> bf16 bits, RNE
    unsigned u = __float_as_uint(f);
    return (u + 0x7FFFu + ((u >> 16) & 1u)) >> 16;
}
__device__ __forceinline__ float bflo(unsigned u){ return __builtin_bit_cast(float, u << 16); }
__device__ __forceinline__ float bfhi(unsigned u){ return __builtin_bit_cast(float, u & 0xFFFF0000u); }

__device__ __forceinline__ uint4 packfrag_u(float4 lo, float4 hi) {
    return make_uint4(bfbits(lo.x) | (bfbits(lo.y) << 16),
                      bfbits(lo.z) | (bfbits(lo.w) << 16),
                      bfbits(hi.x) | (bfbits(hi.y) << 16),
                      bfbits(hi.z) | (bfbits(hi.w) << 16));
}

// ---- DPP cross-lane (row = 16 lanes; row_ror:n = 0x120+n) -------------------
template<int CTRL>
__device__ __forceinline__ int dpp_mov(int v) {
    return __builtin_amdgcn_update_dpp(0, v, CTRL, 0xF, 0xF, true);
}
template<int CTRL>
__device__ __forceinline__ float dpp_addf(float v) {
    return v + __builtin_bit_cast(float, dpp_mov<CTRL>(__builtin_bit_cast(int, v)));
}
template<int CTRL>
__device__ __forceinline__ unsigned dpp_maxu(unsigned v) {
    return umax_(v, (unsigned)dpp_mov<CTRL>((int)v));
}
__device__ __forceinline__ float rowsum16(float v) {
    v = dpp_addf<0x128>(v); v = dpp_addf<0x124>(v);
    v = dpp_addf<0x122>(v); v = dpp_addf<0x121>(v);
    return v;
}
__device__ __forceinline__ unsigned rowmax16(unsigned v) {
    v = dpp_maxu<0x128>(v); v = dpp_maxu<0x124>(v);
    v = dpp_maxu<0x122>(v); v = dpp_maxu<0x121>(v);
    return v;
}

// ---------------- Kernel 1 (fused prep): transpose + xx + bf16 + y/z MFMA ----------------
// 256 blocks x 128 threads (2 waves); block owns 128 consecutive n-rows.
// The bf16 rows staged in LDS for the coalesced xbf store are consumed directly
// by the y/z MFMA (no global round-trip); W fragments packed once per block.
__global__ __launch_bounds__(128) void k_prep(
    const float* __restrict__ x, const float* __restrict__ W,
    float* __restrict__ xt, unsigned short* __restrict__ xbf,
    unsigned short* __restrict__ ybf, unsigned short* __restrict__ zbf,
    double* __restrict__ xxd, float* __restrict__ xxc)
{
    __shared__ __align__(16) float tS[128 * 33];   // 16896 B staging (fp32, then bf16)
    __shared__ __align__(16) uint4 WfS[1024];      // 16384 B W fragments
    int tid = threadIdx.x;
    int b   = blockIdx.x >> 5;
    int nb0 = (blockIdx.x & 31) << 7;
    int n   = nb0 + tid;
    size_t brow = (size_t)b * NN;

    // pack W fragments -> LDS (each thread 8 entries); layout (o*16 + sel*4 + quad)
    {
        const float4* W4 = (const float4*)W;       // W row = 32 float4
        #pragma unroll
        for (int i = 0; i < 8; ++i) {
            int idx = i*128 + tid;                 // 0..1023
            int o = idx >> 4, sel = (idx >> 2) & 3, quad = idx & 3;
            float4 lo = W4[(size_t)o*32 + sel*8 + quad*2];
            float4 hi = W4[(size_t)o*32 + sel*8 + quad*2 + 1];
            WfS[idx] = packfrag_u(lo, hi);
        }
    }

    float xv[64];
    double xx = 0.0;
    #pragma unroll
    for (int cc = 0; cc < 64; ++cc) {
        float v = x[((size_t)(b*64 + cc) << 12) + n];
        xv[cc] = v;
        xx += (double)v * (double)v;
    }
    xxd[brow + n] = xx;
    xxc[brow + n] = 1024.f - (float)xx;     // biased so scores are always > 0

    // fp32 xt: two 32-channel halves through LDS (line-coalesced stores)
    #pragma unroll 1
    for (int h = 0; h < 2; ++h) {
        #pragma unroll
        for (int cc = 0; cc < 32; ++cc) tS[tid*33 + cc] = xv[h*32 + cc];
        __syncthreads();
        #pragma unroll
        for (int i = 0; i < 8; ++i) {
            int idx = i*128 + tid;              // 0..1023 float4s
            int r = idx >> 3, c4 = idx & 7;
            float4 v = make_float4(tS[r*33 + 4*c4],     tS[r*33 + 4*c4 + 1],
                                   tS[r*33 + 4*c4 + 2], tS[r*33 + 4*c4 + 3]);
            *(float4*)(xt + (brow + nb0 + r)*64 + h*32 + 4*c4) = v;
        }
        __syncthreads();
    }
    // bf16 rows -> LDS (stays resident for the MFMA below) + coalesced xbf store
    unsigned* tU = (unsigned*)tS;
    {
        unsigned pk[32];
        #pragma unroll
        for (int i = 0; i < 32; ++i)
            pk[i] = bfbits(xv[2*i]) | (bfbits(xv[2*i+1]) << 16);
        #pragma unroll
        for (int i = 0; i < 32; ++i) tU[tid*33 + i] = pk[i];
        __syncthreads();
        uint4* xb4 = (uint4*)xbf;
        #pragma unroll
        for (int i = 0; i < 8; ++i) {
            int idx = i*128 + tid;
            int r = idx >> 3, u4 = idx & 7;
            uint4 v = make_uint4(tU[r*33 + 4*u4],     tU[r*33 + 4*u4 + 1],
                                 tU[r*33 + 4*u4 + 2], tU[r*33 + 4*u4 + 3]);
            xb4[(brow + nb0 + r)*8 + u4] = v;
        }
    }
    // no further LDS writes -> bf16 rows + WfS readable without extra barrier

    // ---- y/z MFMA: 2 waves x 4 tiles of 16 rows ----
    int w = tid >> 6, lane = tid & 63, quad = lane >> 4, c = lane & 15;
    #pragma unroll 1
    for (int t = 0; t < 4; ++t) {
        int lrow = w*64 + t*16 + c;
        uint4 xb0 = *(const uint4*)(tU + lrow*33 + quad*4);
        uint4 xb1 = *(const uint4*)(tU + lrow*33 + 16 + quad*4);
        bf16x8 bb0 = __builtin_bit_cast(bf16x8, xb0);
        bf16x8 bb1 = __builtin_bit_cast(bf16x8, xb1);
        int nw = nb0 + lrow;
        #pragma unroll 1
        for (int ot = 0; ot < 4; ++ot) {
            const uint4* wf = WfS + (ot*16 + c)*16 + quad;
            bf16x8 w1a = __builtin_bit_cast(bf16x8, wf[0]);
            bf16x8 w1b = __builtin_bit_cast(bf16x8, wf[4]);
            bf16x8 w2a = __builtin_bit_cast(bf16x8, wf[8]);
            bf16x8 w2b = __builtin_bit_cast(bf16x8, wf[12]);
            f32x4 acc1 = __builtin_amdgcn_mfma_f32_16x16x32_bf16(
                w1a, bb0, (f32x4){0.f,0.f,0.f,0.f}, 0, 0, 0);
            acc1 = __builtin_amdgcn_mfma_f32_16x16x32_bf16(w1b, bb1, acc1, 0, 0, 0);
            f32x4 acc2 = __builtin_amdgcn_mfma_f32_16x16x32_bf16(
                w2a, bb0, (f32x4){0.f,0.f,0.f,0.f}, 0, 0, 0);
            acc2 = __builtin_amdgcn_mfma_f32_16x16x32_bf16(w2b, bb1, acc2, 0, 0, 0);
            // thread (quad,c): o = ot*16 + quad*4 + j, n = nw; y=acc1, z=acc1+acc2
            float z0 = acc1[0]+acc2[0], z1 = acc1[1]+acc2[1],
                  z2 = acc1[2]+acc2[2], z3 = acc1[3]+acc2[3];
            size_t obase = (brow + nw) * 64 + (ot*16 + quad*4);
            *(uint2*)(ybf + obase) = make_uint2(
                bfbits(acc1[0]) | (bfbits(acc1[1]) << 16),
                bfbits(acc1[2]) | (bfbits(acc1[3]) << 16));
            *(uint2*)(zbf + obase) = make_uint2(
                bfbits(z0) | (bfbits(z1) << 16),
                bfbits(z2) | (bfbits(z3) << 16));
        }
    }
}

// ---------------- Kernel 2 (fused): 32-n tile Gram + top-12 keys + refine ----------------
// R9-verbatim (171 us, VGPR 56, no spill). 1024 blocks x 256 = 4 blocks/CU (grid-capped).
__global__ __launch_bounds__(256, 4) void k_main(
    const unsigned short* __restrict__ xbf, const float* __restrict__ xt,
    const double* __restrict__ xxd, const float* __restrict__ xxc,
    const unsigned short* __restrict__ ybf, const unsigned short* __restrict__ zbf,
    const float* __restrict__ gamma, const float* __restrict__ beta,
    const float* __restrict__ rmean, const float* __restrict__ rvar,
    float* __restrict__ out)
{
    __shared__ __align__(16) unsigned keysL[32 * KP];     // 25088 B (outS aliases this)
    __shared__ __align__(16) unsigned gselS[32 * EXTRG];  // 3 KB
    __shared__ int      m26S[32 * NF];                    // 3 KB
    __shared__ double   d26S[32 * NF];                    // 6 KB
    __shared__ int      selS[32 * KK];                    // 2.5 KB
    float* outS = (float*)keysL;                          // 64 o x pitch 33 = 8448 B

    int tid  = threadIdx.x;
    int w    = tid >> 6, lane = tid & 63;
    int quad = lane >> 4, c = lane & 15;
    int b  = blockIdx.x & 7;                 // batch <-> XCD affinity
    int n0 = (blockIdx.x >> 3) << 5;         // 32-n tile
    size_t brow = (size_t)b * NN;

    const uint4* xb = (const uint4*)xbf;     // one row = 8 uint4

    // B fragments for the two fixed n-tiles
    size_t nr0 = (brow + n0 + c) * 8 + quad;
    size_t nr1 = (brow + n0 + 16 + c) * 8 + quad;
    bf16x8 b00 = __builtin_bit_cast(bf16x8, xb[nr0]);
    bf16x8 b01 = __builtin_bit_cast(bf16x8, xb[nr0 + 4]);
    bf16x8 b10 = __builtin_bit_cast(bf16x8, xb[nr1]);
    bf16x8 b11 = __builtin_bit_cast(bf16x8, xb[nr1 + 4]);

    unsigned kA[LL], kB[LL];
    #pragma unroll
    for (int i = 0; i < LL; ++i) { kA[i] = 0u; kB[i] = 0u; }

    // A stream, prefetch depth 2
    size_t abase = (brow + 16*w + c) * 8 + quad;
    size_t xxb   = brow + 16*w + quad*4;
    uint4  a0p[2], a1p[2];
    float4 xxp[2];
    a0p[0] = xb[abase];       a1p[0] = xb[abase + 4];
    a0p[1] = xb[abase + 512]; a1p[1] = xb[abase + 516];
    xxp[0] = *(const float4*)(xxc + xxb);
    xxp[1] = *(const float4*)(xxc + xxb + 64);

    #pragma unroll 2
    for (int chunk = 0; chunk < 64; ++chunk) {
        int s = chunk & 1;                   // constant after unroll-2
        uint4 ca0 = a0p[s], ca1 = a1p[s];
        float4 x4 = xxp[s];
        if (chunk < 62) {
            size_t nb = abase + (size_t)(chunk + 2) * 512;
            a0p[s] = xb[nb]; a1p[s] = xb[nb + 4];
            xxp[s] = *(const float4*)(xxc + xxb + (chunk + 2)*64);
        }
        f32x4 accA = __builtin_amdgcn_mfma_f32_16x16x32_bf16(
            __builtin_bit_cast(bf16x8, ca0), b00, (f32x4){0.f,0.f,0.f,0.f}, 0, 0, 0);
        accA = __builtin_amdgcn_mfma_f32_16x16x32_bf16(
            __builtin_bit_cast(bf16x8, ca1), b01, accA, 0, 0, 0);
        f32x4 accB = __builtin_amdgcn_mfma_f32_16x16x32_bf16(
            __builtin_bit_cast(bf16x8, ca0), b10, (f32x4){0.f,0.f,0.f,0.f}, 0, 0, 0);
        accB = __builtin_amdgcn_mfma_f32_16x16x32_bf16(
            __builtin_bit_cast(bf16x8, ca1), b11, accB, 0, 0, 0);

        unsigned gid = (unsigned)((chunk << 4) | (w << 2) | quad);
        {   // tile 0: n = n0+c
            float s0 = fmaf(2.f, accA[0], x4.x), s1 = fmaf(2.f, accA[1], x4.y);
            float s2 = fmaf(2.f, accA[2], x4.z), s3 = fmaf(2.f, accA[3], x4.w);
            float gm = fmaxf(fmaxf(s0, s1), fmaxf(s2, s3));
            unsigned key = (__float_as_uint(gm) & 0xFFFFFC00u) | gid;
            #pragma unroll
            for (int t = 0; t < LL; ++t) {
                unsigned mx = umax_(kA[t], key);
                key = umin_(kA[t], key);
                kA[t] = mx;
            }
        }
        {   // tile 1: n = n0+16+c  (independent CE chain - interleaves with tile 0)
            float s0 = fmaf(2.f, accB[0], x4.x), s1 = fmaf(2.f, accB[1], x4.y);
            float s2 = fmaf(2.f, accB[2], x4.z), s3 = fmaf(2.f, accB[3], x4.w);
            float gm = fmaxf(fmaxf(s0, s1), fmaxf(s2, s3));
            unsigned key = (__float_as_uint(gm) & 0xFFFFFC00u) | gid;
            #pragma unroll
            for (int t = 0; t < LL; ++t) {
                unsigned mx = umax_(kB[t], key);
                key = umin_(kB[t], key);
                kB[t] = mx;
            }
        }
    }

    // park lists: row = 16*tile + c, list id = 4w+quad
    {
        uint4* kd0 = (uint4*)(keysL + c*KP + (w*4 + quad)*LL);
        kd0[0] = make_uint4(kA[0], kA[1], kA[2],  kA[3]);
        kd0[1] = make_uint4(kA[4], kA[5], kA[6],  kA[7]);
        kd0[2] = make_uint4(kA[8], kA[9], kA[10], kA[11]);
        uint4* kd1 = (uint4*)(keysL + (16 + c)*KP + (w*4 + quad)*LL);
        kd1[0] = make_uint4(kB[0], kB[1], kB[2],  kB[3]);
        kd1[1] = make_uint4(kB[4], kB[5], kB[6],  kB[7]);
        kd1[2] = make_uint4(kB[8], kB[9], kB[10], kB[11]);
    }
    __syncthreads();

    // ================= refine (quarter-wave per row; 2 rows per thread-group) ========
    int r = tid >> 4, g = tid & 15;

    // pass 1: stage 1+2 for both rows -> gselS; after this keysL is dead
    #pragma unroll 1
    for (int rr = 0; rr < 2; ++rr) {
        int row = rr*16 + r;
        unsigned mk[LL];
        {
            const uint4* ks = (const uint4*)(keysL + row*KP + g*LL);
            uint4 k0 = ks[0], k1 = ks[1], k2 = ks[2];
            mk[0]=k0.x; mk[1]=k0.y; mk[2]=k0.z;  mk[3]=k0.w;
            mk[4]=k1.x; mk[5]=k1.y; mk[6]=k1.z;  mk[7]=k1.w;
            mk[8]=k2.x; mk[9]=k2.y; mk[10]=k2.z; mk[11]=k2.w;
        }
        #pragma unroll 1
        for (int it = 0; it < EXTRG; ++it) {
            unsigned vm = rowmax16(mk[0]);
            bool win = (mk[0] == vm);
            #pragma unroll
            for (int q = 0; q < LL-1; ++q) mk[q] = win ? mk[q+1] : mk[q];
            mk[LL-1] = win ? 0u : mk[LL-1];
            if (g == (it & 15)) gselS[row*EXTRG + it] = vm;
        }
    }
    __syncthreads();   // keysL reads done -> outS (alias) may now be written

    // pass 2: stages 3..6 per row
    #pragma unroll 1
    for (int rr = 0; rr < 2; ++rr) {
        int row = rr*16 + r;
        int n = n0 + row;
        uint2 anb = *(const uint2*)(xbf + (brow + n) * 64 + 4*g);
        float an0 = bflo(anb.x), an1 = bfhi(anb.x),
              an2 = bflo(anb.y), an3 = bfhi(anb.y);

        // stage 3: bf16 cooperative rescore of 96 candidates
        unsigned myk[6];
        #pragma unroll
        for (int j = 0; j < 6; ++j) {
            uint4 Gj = *(const uint4*)(gselS + row*EXTRG + 4*j);
            unsigned gk4[4] = {Gj.x, Gj.y, Gj.z, Gj.w};
            #pragma unroll
            for (int h = 0; h < 2; ++h) {
                uint2 vbs[8]; float xxm[8];
                #pragma unroll
                for (int u = 0; u < 8; ++u) {
                    int t = h*8 + u;
                    int m = (int)((gk4[t >> 2] & 1023u) << 2) | (t & 3);
                    vbs[u] = *(const uint2*)(xbf + (brow + m) * 64 + 4*g);
                    xxm[u] = xxc[brow + m];
                }
                #pragma unroll
                for (int u = 0; u < 8; ++u) {
                    int t = h*8 + u;
                    float p = an0 * bflo(vbs[u].x);
                    p = fmaf(an1, bfhi(vbs[u].x), p);
                    p = fmaf(an2, bflo(vbs[u].y), p);
                    p = fmaf(an3, bfhi(vbs[u].y), p);
                    p = rowsum16(p);
                    float sc = fmaf(2.f, p, xxm[u]);
                    unsigned key = (__float_as_uint(sc) & 0xFFFFFF80u) | (unsigned)(j*16 + t);
                    if (t == g) myk[j] = key;
                }
            }
        }
        #pragma unroll
        for (int a = 1; a < 6; ++a)
            #pragma unroll
            for (int q = a; q > 0; --q) {
                unsigned lo = umin_(myk[q-1], myk[q]);
                myk[q-1] = umax_(myk[q-1], myk[q]);
                myk[q] = lo;
            }

        // stage 3.5: pop-shift merge -> exact top-NF of the 96 fp32 keys
        #pragma unroll 1
        for (int it = 0; it < NF; ++it) {
            unsigned vm = rowmax16(myk[0]);
            bool win = (myk[0] == vm);
            #pragma unroll
            for (int q = 0; q < 5; ++q) myk[q] = win ? myk[q+1] : myk[q];
            myk[5] = win ? 0u : myk[5];
            if (g == (it & 15)) {
                int i = (int)(vm & 127u);
                unsigned gk = gselS[row*EXTRG + (i >> 2)];
                m26S[row*NF + it] = (int)((gk & 1023u) << 2) | (i & 3);
            }
        }

        // stage 4: fp64 per-lane full dots (lane = candidate)
        #pragma unroll
        for (int round = 0; round < 2; ++round) {
            int t = round*16 + g;
            if (t < NF) {
                int m = m26S[row*NF + t];
                const float4* xm = (const float4*)(xt + (brow + m) * 64);
                const float4* xn = (const float4*)(xt + (brow + n) * 64);
                double acc0 = 0.0, acc1 = 0.0;
                #pragma unroll
                for (int i = 0; i < 8; ++i) {
                    float4 v0 = xm[2*i], a0 = xn[2*i];
                    float4 v1 = xm[2*i+1], a1 = xn[2*i+1];
                    acc0 += (double)a0.x*(double)v0.x + (double)a0.y*(double)v0.y
                          + (double)a0.z*(double)v0.z + (double)a0.w*(double)v0.w;
                    acc1 += (double)a1.x*(double)v1.x + (double)a1.y*(double)v1.y
                          + (double)a1.z*(double)v1.z + (double)a1.w*(double)v1.w;
                }
                d26S[row*NF + t] = 2.0*(acc0 + acc1) - xxd[brow + m];
            }
        }

        // stage 5: exact top-20 set by rank counting
        #pragma unroll
        for (int round = 0; round < 2; ++round) {
            int t = round*16 + g;
            if (t < NF) {
                double st = d26S[row*NF + t];
                int cnt = 0;
                #pragma unroll
                for (int p = 0; p < NF; ++p) cnt += (d26S[row*NF + p] > st) ? 1 : 0;
                if (cnt < KK) selS[row*KK + cnt] = m26S[row*NF + t];
            }
        }

        // stage 6: gather y (bf16), min/max per o, epilogue -> outS (aliased)
        float mn[4] = { __builtin_inff(), __builtin_inff(), __builtin_inff(), __builtin_inff() };
        float mx[4] = { -__builtin_inff(), -__builtin_inff(), -__builtin_inff(), -__builtin_inff() };
        #pragma unroll
        for (int hb = 0; hb < 2; ++hb) {
            uint2 yb[10];
            #pragma unroll
            for (int k = 0; k < 10; ++k)
                yb[k] = *(const uint2*)(ybf + (brow + selS[row*KK + hb*10 + k]) * 64 + 4*g);
            #pragma unroll
            for (int k = 0; k < 10; ++k) {
                float y0 = bflo(yb[k].x), y1 = bfhi(yb[k].x),
                      y2 = bflo(yb[k].y), y3 = bfhi(yb[k].y);
                mn[0] = fminf(mn[0], y0); mx[0] = fmaxf(mx[0], y0);
                mn[1] = fminf(mn[1], y1); mx[1] = fmaxf(mx[1], y1);
                mn[2] = fminf(mn[2], y2); mx[2] = fmaxf(mx[2], y2);
                mn[3] = fminf(mn[3], y3); mx[3] = fmaxf(mx[3], y3);
            }
        }
        uint2 zb = *(const uint2*)(zbf + (brow + n) * 64 + 4*g);
        float zz[4] = {bflo(zb.x), bfhi(zb.x), bflo(zb.y), bfhi(zb.y)};
        #pragma unroll
        for (int j = 0; j < 4; ++j) {
            int o = 4*g + j;
            float inv  = gamma[o] / sqrtf(rvar[o] + 1e-5f);
            float bias = beta[o] - rmean[o] * inv;
            float ysel = (inv >= 0.f) ? mn[j] : mx[j];
            float h = (zz[j] - ysel) * inv + bias;
            outS[o*33 + row] = (h >= 0.f) ? h : 0.2f * h;
        }
    }
    __syncthreads();   // cross-wave: output transpose
    {
        int o = tid >> 2, q = tid & 3;
        float* ob = outS + o*33;
        float4 v0 = make_float4(ob[4*q],      ob[4*q + 1],  ob[4*q + 2],  ob[4*q + 3]);
        float4 v1 = make_float4(ob[16 + 4*q], ob[17 + 4*q], ob[18 + 4*q], ob[19 + 4*q]);
        float* op = out + ((size_t)(b*64 + o) << 12) + n0;
        *(float4*)(op + 4*q)      = v0;
        *(float4*)(op + 16 + 4*q) = v1;
    }
}

extern "C" void kernel_launch(void* const* d_in, const int* in_sizes, int n_in,
                              void* d_out, int out_size, void* d_ws, size_t ws_size,
                              hipStream_t stream) {
    const float* x     = (const float*)d_in[0];
    const float* W     = (const float*)d_in[1];
    const float* gamma = (const float*)d_in[2];
    const float* beta  = (const float*)d_in[3];
    const float* rmean = (const float*)d_in[4];
    const float* rvar  = (const float*)d_in[5];
    float* out = (float*)d_out;

    char* ws = (char*)d_ws;
    float*          xt  = (float*)          (ws);                          //  8 MB
    unsigned short* xbf = (unsigned short*) (ws + ((size_t) 8 << 20));     //  4 MB
    unsigned short* ybf = (unsigned short*) (ws + ((size_t)12 << 20));     //  4 MB
    unsigned short* zbf = (unsigned short*) (ws + ((size_t)16 << 20));     //  4 MB
    double*         xxd = (double*)         (ws + ((size_t)20 << 20));     // 256 KB
    float*          xxc = (float*)          (ws + ((size_t)20 << 20) + (512 << 10)); // 128 KB

    k_prep<<< 256, 128, 0, stream>>>(x, W, xt, xbf, ybf, zbf, xxd, xxc);
    k_main<<<1024, 256, 0, stream>>>(xbf, xt, xxd, xxc, ybf, zbf,
                                     gamma, beta, rmean, rvar, out);
}